// Round 1
// baseline (786.588 us; speedup 1.0000x reference)
//
#include <hip/hip_runtime.h>
#include <hip/hip_bf16.h>

// Problem constants
#define BB 32
#define TT 1500
#define TP 1536      // T padded to 12*128 for GEMM tiles
#define EE 512
#define HH 4
#define AA 512
#define NN 2048      // H*A
#define CC 10
#define KCONV 201
#define KAUG 576     // 512 enc + 40 conv + 24 zero pad (18 k-steps of 32)

typedef __attribute__((ext_vector_type(8))) __bf16 bf16x8;
typedef __attribute__((ext_vector_type(4))) float f32x4;

// ---------- helpers ----------
__device__ __forceinline__ unsigned short f2bf(float x) {
    unsigned int u = __float_as_uint(x);
    u = (u + 0x7fffu + ((u >> 16) & 1u)) >> 16;   // RNE, inputs always finite
    return (unsigned short)u;
}
__device__ __forceinline__ float bf2f(unsigned short u) {
    return __uint_as_float(((unsigned int)u) << 16);
}
__device__ __forceinline__ void glds16(const void* g, void* l) {
    __builtin_amdgcn_global_load_lds(
        (const __attribute__((address_space(1))) unsigned int*)g,
        (__attribute__((address_space(3))) unsigned int*)l, 16, 0, 0);
}

// ---------- K1: build W_t planes [N=2048][KAUG=576], hi/lo bf16 ----------
__global__ void k_wt(const float* __restrict__ w_enc, const float* __restrict__ w_conv,
                     unsigned short* __restrict__ Whi, unsigned short* __restrict__ Wlo) {
    int idx = blockIdx.x * 256 + threadIdx.x;
    if (idx >= NN * KAUG) return;
    int n = idx / KAUG, k = idx % KAUG;
    int h = n >> 9, a = n & 511;
    float val = 0.f;
    if (k < 512) {
        val = w_enc[((size_t)h * 512 + k) * 512 + a];
    } else if (k < 552) {
        int j = k - 512; int h2 = j / 10, c = j % 10;
        if (h2 == h) val = w_conv[((size_t)h * 10 + c) * 512 + a];
    }
    unsigned short hi = f2bf(val);
    Whi[idx] = hi;
    Wlo[idx] = f2bf(val - bf2f(hi));
}

// ---------- K2: dec_a[b][n] = b_enc[n] + sum_d dec[b][d]*w_dec[h][d][a] ----------
__global__ void k_dec(const float* __restrict__ dec_out, const float* __restrict__ w_dec,
                      const float* __restrict__ b_enc, float* __restrict__ dec_a) {
    int idx = blockIdx.x * 256 + threadIdx.x;     // 65536
    int b = idx >> 11, n = idx & 2047;
    int h = n >> 9, a = n & 511;
    float acc = b_enc[n];
    const float* dp = dec_out + (size_t)b * 512;
    const float* wp = w_dec + (size_t)h * 512 * 512 + a;
    for (int d = 0; d < 512; ++d) acc += dp[d] * wp[(size_t)d * 512];
    dec_a[idx] = acc;
}

// ---------- K3: enc_out f32 -> A planes cols [0,512) ----------
__global__ void k_enc(const float* __restrict__ enc,
                      unsigned short* __restrict__ Ahi, unsigned short* __restrict__ Alo) {
    long idx = (long)blockIdx.x * 256 + threadIdx.x;   // 6,144,000 float4s
    if (idx >= 6144000L) return;
    long f = idx * 4;
    int b = (int)(f / 768000);
    int r = (int)(f % 768000);
    int t = r >> 9, e = r & 511;
    float4 vv = *reinterpret_cast<const float4*>(enc + f);
    ushort4 h4, l4;
    h4.x = f2bf(vv.x); l4.x = f2bf(vv.x - bf2f(h4.x));
    h4.y = f2bf(vv.y); l4.y = f2bf(vv.y - bf2f(h4.y));
    h4.z = f2bf(vv.z); l4.z = f2bf(vv.z - bf2f(h4.z));
    h4.w = f2bf(vv.w); l4.w = f2bf(vv.w - bf2f(h4.w));
    size_t o = ((size_t)b * TP + t) * KAUG + e;
    *reinterpret_cast<ushort4*>(Ahi + o) = h4;
    *reinterpret_cast<ushort4*>(Alo + o) = l4;
}

// ---------- K4: zero-fill A padding (rows >=1500 all cols; cols [552,576) rows <1500) ----------
__global__ void k_pad(unsigned short* __restrict__ Ahi, unsigned short* __restrict__ Alo) {
    int idx = blockIdx.x * 256 + threadIdx.x;
    const int tot1 = BB * 36 * KAUG;        // 663552
    const int tot2 = BB * TT * 24;          // 1152000
    size_t o;
    if (idx < tot1) {
        int b = idx / (36 * KAUG); int r = idx % (36 * KAUG);
        int t = 1500 + r / KAUG;   int k = r % KAUG;
        o = ((size_t)b * TP + t) * KAUG + k;
    } else if (idx < tot1 + tot2) {
        int j = idx - tot1;
        int b = j / (TT * 24); int r = j % (TT * 24);
        int t = r / 24;        int k = 552 + r % 24;
        o = ((size_t)b * TP + t) * KAUG + k;
    } else return;
    Ahi[o] = 0; Alo[o] = 0;
}

// ---------- K5: grouped conv over aw_step -> A planes cols [512,552) ----------
__global__ __launch_bounds__(256) void k_conv(const float* __restrict__ aw_step,
                                              const float* __restrict__ conv_k,
                                              unsigned short* __restrict__ Ahi,
                                              unsigned short* __restrict__ Alo) {
    const int tch = blockIdx.x;   // 0..5
    const int hc  = blockIdx.y;   // 0..39  (h*10+c)
    const int b   = blockIdx.z;
    const int h   = hc / 10;
    const int t0  = tch * 256;
    __shared__ float sAw[456];
    __shared__ float sK[KCONV];
    const int tid = threadIdx.x;
    for (int i = tid; i < 456; i += 256) {
        int ts = t0 - 100 + i;
        sAw[i] = (ts >= 0 && ts < TT) ? aw_step[((size_t)b * TT + ts) * HH + h] : 0.f;
    }
    if (tid < KCONV) sK[tid] = conv_k[(size_t)hc * KCONV + tid];
    __syncthreads();
    int t = t0 + tid;
    if (t < TT) {
        float acc = 0.f;
        for (int k = 0; k < KCONV; ++k) acc += sAw[tid + k] * sK[k];
        size_t o = ((size_t)b * TP + t) * KAUG + 512 + hc;
        unsigned short hi = f2bf(acc);
        Ahi[o] = hi; Alo[o] = f2bf(acc - bf2f(hi));
    }
}

// ---------- K6: fused split-bf16 MFMA GEMM + (+dec_a, tanh, *v, reduce-A) -> energy ----------
__global__ __launch_bounds__(256) void k_gemm(
    const unsigned short* __restrict__ Ahi, const unsigned short* __restrict__ Alo,
    const unsigned short* __restrict__ Whi, const unsigned short* __restrict__ Wlo,
    const float* __restrict__ dec_a, const float* __restrict__ vvec,
    float* __restrict__ energy) {
    __shared__ unsigned short lsAhi[128 * 32], lsAlo[128 * 32];
    __shared__ unsigned short lsBhi[128 * 32], lsBlo[128 * 32];
    const int ntile = blockIdx.x, mtile = blockIdx.y, b = blockIdx.z;
    const int tid = threadIdx.x;
    const int lane = tid & 63, wave = tid >> 6;
    const int wm = wave >> 1, wn = wave & 1;
    const int m0 = mtile * 128, n0 = ntile * 128;

    f32x4 acc[4][4];
#pragma unroll
    for (int i = 0; i < 4; i++)
#pragma unroll
        for (int j = 0; j < 4; j++) acc[i][j] = (f32x4){0.f, 0.f, 0.f, 0.f};

    const int row = tid >> 2;
    const int ko  = (tid & 3) * 8;
    const size_t abase = ((size_t)b * TP + m0 + row) * KAUG + ko;
    const size_t bbase = ((size_t)n0 + row) * KAUG + ko;
    const int l1 = row * 32 + ko;        // == tid*8 elements == tid*16 bytes (wave-uniform+lane*16)
    const int l2 = l1 + 64 * 32;

    for (int ks = 0; ks < 18; ++ks) {
        const int k0 = ks * 32;
        __syncthreads();
        glds16(Ahi + abase + k0,                    &lsAhi[l1]);
        glds16(Ahi + abase + k0 + (size_t)64 * KAUG, &lsAhi[l2]);
        glds16(Alo + abase + k0,                    &lsAlo[l1]);
        glds16(Alo + abase + k0 + (size_t)64 * KAUG, &lsAlo[l2]);
        glds16(Whi + bbase + k0,                    &lsBhi[l1]);
        glds16(Whi + bbase + k0 + (size_t)64 * KAUG, &lsBhi[l2]);
        glds16(Wlo + bbase + k0,                    &lsBlo[l1]);
        glds16(Wlo + bbase + k0 + (size_t)64 * KAUG, &lsBlo[l2]);
        asm volatile("s_waitcnt vmcnt(0)" ::: "memory");
        __syncthreads();

        const int ar = wm * 64, br = wn * 64;
        const int fo = (lane & 15) * 32 + (lane >> 4) * 8;
        bf16x8 ah[4], al[4], bh[4], bl[4];
#pragma unroll
        for (int i = 0; i < 4; i++) {
            ah[i] = *(const bf16x8*)&lsAhi[(ar + i * 16) * 32 + fo];
            al[i] = *(const bf16x8*)&lsAlo[(ar + i * 16) * 32 + fo];
            bh[i] = *(const bf16x8*)&lsBhi[(br + i * 16) * 32 + fo];
            bl[i] = *(const bf16x8*)&lsBlo[(br + i * 16) * 32 + fo];
        }
#pragma unroll
        for (int i = 0; i < 4; i++)
#pragma unroll
            for (int j = 0; j < 4; j++) {
                acc[i][j] = __builtin_amdgcn_mfma_f32_16x16x32_bf16(ah[i], bh[j], acc[i][j], 0, 0, 0);
                acc[i][j] = __builtin_amdgcn_mfma_f32_16x16x32_bf16(ah[i], bl[j], acc[i][j], 0, 0, 0);
                acc[i][j] = __builtin_amdgcn_mfma_f32_16x16x32_bf16(al[i], bh[j], acc[i][j], 0, 0, 0);
            }
    }

    // Epilogue: x = acc + dec_a[b][n]; energy += tanh(x)*v[n], reduced over head's A-dim
    const int h = ntile >> 2;            // 128-wide tile lies inside one head (512 cols)
    const int kg = lane >> 4;
    float dv[4], vv[4];
#pragma unroll
    for (int j = 0; j < 4; j++) {
        int ng = n0 + wn * 64 + j * 16 + (lane & 15);
        dv[j] = dec_a[(size_t)b * NN + ng];
        vv[j] = vvec[ng];
    }
#pragma unroll
    for (int i = 0; i < 4; i++) {
        float part[4] = {0.f, 0.f, 0.f, 0.f};
#pragma unroll
        for (int j = 0; j < 4; j++)
#pragma unroll
            for (int r = 0; r < 4; r++)
                part[r] += tanhf(acc[i][j][r] + dv[j]) * vv[j];
#pragma unroll
        for (int r = 0; r < 4; r++) {
            float s = part[r];
            s += __shfl_xor(s, 1, 64);
            s += __shfl_xor(s, 2, 64);
            s += __shfl_xor(s, 4, 64);
            s += __shfl_xor(s, 8, 64);
            if ((lane & 15) == 0) {
                int t = m0 + wm * 64 + i * 16 + kg * 4 + r;
                if (t < TT)
                    atomicAdd(&energy[((size_t)b * HH + h) * TP + t], s);
            }
        }
    }
}

// ---------- K7: masked softmax over time (replicates energy * (+1 / -1024) mask) ----------
__global__ __launch_bounds__(256) void k_softmax(const float* __restrict__ energy,
                                                 const int* __restrict__ x_lens,
                                                 float* __restrict__ aw) {
    const int b = blockIdx.x >> 2, h = blockIdx.x & 3;
    const int tid = threadIdx.x;
    __shared__ float sE[TT];
    __shared__ float red[256];
    const int xlen = x_lens[b];
    float lmax = -3.4e38f;
    for (int t = tid; t < TT; t += 256) {
        float e = energy[((size_t)b * HH + h) * TP + t];
        float m = (t < xlen) ? e : e * -1024.0f;
        sE[t] = m;
        lmax = fmaxf(lmax, m);
    }
    red[tid] = lmax; __syncthreads();
    for (int s = 128; s > 0; s >>= 1) { if (tid < s) red[tid] = fmaxf(red[tid], red[tid + s]); __syncthreads(); }
    float mx = red[0]; __syncthreads();
    float lsum = 0.f;
    for (int t = tid; t < TT; t += 256) {
        float ex = expf(sE[t] - mx);
        sE[t] = ex; lsum += ex;
    }
    red[tid] = lsum; __syncthreads();
    for (int s = 128; s > 0; s >>= 1) { if (tid < s) red[tid] += red[tid + s]; __syncthreads(); }
    float sum = red[0];
    for (int t = tid; t < TT; t += 256)
        aw[((size_t)b * TT + t) * HH + h] = sE[t] / sum;
}

// ---------- K8: ctx_h[b][h][e] = sum_t aw[b][t][h] * enc[b][t][e] ----------
__global__ __launch_bounds__(512) void k_ctx(const float* __restrict__ enc,
                                             const float* __restrict__ aw,
                                             float* __restrict__ ctx_h) {
    const int chunk = blockIdx.x, b = blockIdx.y;
    const int t0 = chunk * 128;
    const int nt = (TT - t0 < 128) ? (TT - t0) : 128;
    __shared__ float sA[128 * 4];
    const int tid = threadIdx.x;
    for (int i = tid; i < nt * 4; i += 512)
        sA[i] = aw[((size_t)b * TT + t0) * HH + i];
    __syncthreads();
    float a0 = 0.f, a1 = 0.f, a2 = 0.f, a3 = 0.f;
    const float* ep = enc + ((size_t)b * TT + t0) * EE + tid;
    for (int tt = 0; tt < nt; ++tt) {
        float ev = ep[(size_t)tt * EE];
        a0 += sA[tt * 4 + 0] * ev; a1 += sA[tt * 4 + 1] * ev;
        a2 += sA[tt * 4 + 2] * ev; a3 += sA[tt * 4 + 3] * ev;
    }
    atomicAdd(&ctx_h[((size_t)b * HH + 0) * EE + tid], a0);
    atomicAdd(&ctx_h[((size_t)b * HH + 1) * EE + tid], a1);
    atomicAdd(&ctx_h[((size_t)b * HH + 2) * EE + tid], a2);
    atomicAdd(&ctx_h[((size_t)b * HH + 3) * EE + tid], a3);
}

// ---------- K9: ctx = ctx_h @ w_mha + b_mha ----------
__global__ void k_mha(const float* __restrict__ ctx_h, const float* __restrict__ w_mha,
                      const float* __restrict__ b_mha, float* __restrict__ out) {
    int idx = blockIdx.x * 256 + threadIdx.x;   // 16384
    int b = idx >> 9, eo = idx & 511;
    float acc = b_mha[eo];
    const float* c = ctx_h + (size_t)b * NN;
    for (int k = 0; k < NN; ++k) acc += c[k] * w_mha[(size_t)k * EE + eo];
    out[(size_t)b * EE + eo] = acc;
}

extern "C" void kernel_launch(void* const* d_in, const int* in_sizes, int n_in,
                              void* d_out, int out_size, void* d_ws, size_t ws_size,
                              hipStream_t stream) {
    (void)in_sizes; (void)n_in; (void)out_size;
    const float* enc    = (const float*)d_in[0];
    const int*   xlen   = (const int*)d_in[1];
    const float* dec    = (const float*)d_in[2];
    const float* aw_in  = (const float*)d_in[3];
    const float* w_enc  = (const float*)d_in[4];
    const float* b_enc  = (const float*)d_in[5];
    const float* w_dec  = (const float*)d_in[6];
    const float* w_conv = (const float*)d_in[7];
    const float* convk  = (const float*)d_in[8];
    const float* v      = (const float*)d_in[9];
    const float* w_mha  = (const float*)d_in[10];
    const float* b_mha  = (const float*)d_in[11];
    float* out = (float*)d_out;

    // ws layout (needs ~119.3 MB)
    char* ws = (char*)d_ws;
    unsigned short* Whi = (unsigned short*)ws;                          // 2,359,296 B
    unsigned short* Wlo = Whi + (size_t)NN * KAUG;                      // 2,359,296 B
    unsigned short* Ahi = (unsigned short*)(ws + 4718592);              // 56,623,104 B
    unsigned short* Alo = Ahi + (size_t)BB * TP * KAUG;                 // 56,623,104 B
    float* dec_a  = (float*)(ws + 117964800);                           //   262,144 B
    float* energy = (float*)(ws + 118226944);                           //   786,432 B
    float* ctx_h  = (float*)(ws + 119013376);                           //   262,144 B
    (void)ws_size;

    hipMemsetAsync(energy, 0, 786432 + 262144, stream);  // energy + ctx_h (contiguous)

    k_wt  <<<dim3((NN * KAUG + 255) / 256), 256, 0, stream>>>(w_enc, w_conv, Whi, Wlo);
    k_dec <<<dim3(256),   256, 0, stream>>>(dec, w_dec, b_enc, dec_a);
    k_enc <<<dim3(24000), 256, 0, stream>>>(enc, Ahi, Alo);
    k_pad <<<dim3(7092),  256, 0, stream>>>(Ahi, Alo);
    k_conv<<<dim3(6, 40, BB), 256, 0, stream>>>(aw_in, convk, Ahi, Alo);
    k_gemm<<<dim3(16, 12, BB), 256, 0, stream>>>(Ahi, Alo, Whi, Wlo, dec_a, v, energy);
    k_softmax<<<dim3(BB * HH), 256, 0, stream>>>(energy, xlen, out + 16384);
    k_ctx <<<dim3(12, BB), 512, 0, stream>>>(enc, out + 16384, ctx_h);
    k_mha <<<dim3(64), 256, 0, stream>>>(ctx_h, w_mha, b_mha, out);
}

// Round 2
// 658.810 us; speedup vs baseline: 1.1940x; 1.1940x over previous
//
#include <hip/hip_runtime.h>
#include <hip/hip_bf16.h>

// Problem constants
#define BB 32
#define TT 1500
#define TP 1536      // T padded to 12*128 for GEMM tiles
#define EE 512
#define HH 4
#define AA 512
#define NN 2048      // H*A
#define CC 10
#define KCONV 201
#define KAUG 576     // 512 enc + 40 conv + 24 zero pad (18 k-steps of 32)

typedef __attribute__((ext_vector_type(8))) __bf16 bf16x8;
typedef __attribute__((ext_vector_type(4))) float f32x4;

// ---------- helpers ----------
__device__ __forceinline__ unsigned short f2bf(float x) {
    unsigned int u = __float_as_uint(x);
    u = (u + 0x7fffu + ((u >> 16) & 1u)) >> 16;   // RNE, inputs always finite
    return (unsigned short)u;
}
__device__ __forceinline__ float bf2f(unsigned short u) {
    return __uint_as_float(((unsigned int)u) << 16);
}
__device__ __forceinline__ void glds16(const void* g, void* l) {
    __builtin_amdgcn_global_load_lds(
        (const __attribute__((address_space(1))) unsigned int*)g,
        (__attribute__((address_space(3))) unsigned int*)l, 16, 0, 0);
}

// Fused prep kernel: block-range dispatch of 5 independent phases.
//   [0,256)            k_dec   dec_a[b][n]
//   [256,7936)         k_conv  grouped conv -> A cols [512,552)
//   [7936,12544)       k_wt    W planes
//   [12544,19636)      k_pad   zero-fill A padding
//   [19636,43636)      k_enc   enc f32 -> A cols [0,512) (Alo gated on tile validity)
#define PREP_DEC0   0
#define PREP_CONV0  256
#define PREP_WT0    7936
#define PREP_PAD0   12544
#define PREP_ENC0   19636
#define PREP_TOTAL  43636

__global__ __launch_bounds__(256) void k_prep(
    const float* __restrict__ enc, const int* __restrict__ xl,
    const float* __restrict__ dec_out, const float* __restrict__ aw_step,
    const float* __restrict__ w_enc, const float* __restrict__ b_enc,
    const float* __restrict__ w_dec, const float* __restrict__ w_conv,
    const float* __restrict__ conv_k,
    unsigned short* __restrict__ Whi, unsigned short* __restrict__ Wlo,
    unsigned short* __restrict__ Ahi, unsigned short* __restrict__ Alo,
    float* __restrict__ dec_a) {
    __shared__ float sbuf[456 + KCONV];
    const int bid = blockIdx.x;
    const int tid = threadIdx.x;

    if (bid < PREP_CONV0) {
        // ---- dec: dec_a[b][n] = b_enc[n] + sum_d dec[b][d]*w_dec[h][d][a] ----
        int idx = bid * 256 + tid;                 // 65536
        int b = idx >> 11, n = idx & 2047;
        int h = n >> 9, a = n & 511;
        float acc = b_enc[n];
        const float* dp = dec_out + (size_t)b * 512;
        const float* wp = w_dec + (size_t)h * 512 * 512 + a;
        for (int d = 0; d < 512; ++d) acc += dp[d] * wp[(size_t)d * 512];
        dec_a[idx] = acc;
    } else if (bid < PREP_WT0) {
        // ---- conv: grouped 1D conv over aw_step -> A cols [512,552) ----
        int r = bid - PREP_CONV0;                  // 7680 = 6*40*32
        const int tch = r % 6;
        const int hc  = (r / 6) % 40;
        const int b   = r / 240;
        const int h   = hc / 10;
        const int t0  = tch * 256;
        float* sAw = sbuf;
        float* sK  = sbuf + 456;
        for (int i = tid; i < 456; i += 256) {
            int ts = t0 - 100 + i;
            sAw[i] = (ts >= 0 && ts < TT) ? aw_step[((size_t)b * TT + ts) * HH + h] : 0.f;
        }
        if (tid < KCONV) sK[tid] = conv_k[(size_t)hc * KCONV + tid];
        __syncthreads();
        int t = t0 + tid;
        if (t < TT) {
            float acc = 0.f;
            for (int k = 0; k < KCONV; ++k) acc += sAw[tid + k] * sK[k];
            size_t o = ((size_t)b * TP + t) * KAUG + 512 + hc;
            unsigned short hi = f2bf(acc);
            Ahi[o] = hi; Alo[o] = f2bf(acc - bf2f(hi));
        }
    } else if (bid < PREP_PAD0) {
        // ---- wt: W planes [N=2048][KAUG], hi/lo ----
        int idx = (bid - PREP_WT0) * 256 + tid;    // 1,179,648
        int n = idx / KAUG, k = idx % KAUG;
        int h = n >> 9, a = n & 511;
        float val = 0.f;
        if (k < 512) {
            val = w_enc[((size_t)h * 512 + k) * 512 + a];
        } else if (k < 552) {
            int j = k - 512; int h2 = j / 10, c = j % 10;
            if (h2 == h) val = w_conv[((size_t)h * 10 + c) * 512 + a];
        }
        unsigned short hi = f2bf(val);
        Whi[idx] = hi;
        Wlo[idx] = f2bf(val - bf2f(hi));
    } else if (bid < PREP_ENC0) {
        // ---- pad: zero rows >=1500 (all cols) + cols [552,576) (rows <1500) ----
        int idx = (bid - PREP_PAD0) * 256 + tid;
        const int tot1 = BB * 36 * KAUG;           // 663552
        const int tot2 = BB * TT * 24;             // 1152000
        size_t o;
        if (idx < tot1) {
            int b = idx / (36 * KAUG); int r2 = idx % (36 * KAUG);
            int t = 1500 + r2 / KAUG;  int k = r2 % KAUG;
            o = ((size_t)b * TP + t) * KAUG + k;
        } else if (idx < tot1 + tot2) {
            int j = idx - tot1;
            int b = j / (TT * 24); int r2 = j % (TT * 24);
            int t = r2 / 24;       int k = 552 + r2 % 24;
            o = ((size_t)b * TP + t) * KAUG + k;
        } else return;
        Ahi[o] = 0; Alo[o] = 0;
    } else {
        // ---- enc: f32 -> A planes cols [0,512); Alo only for 3-product tiles ----
        long idx = (long)(bid - PREP_ENC0) * 256 + tid;   // 6,144,000 float4s
        if (idx >= 6144000L) return;
        long f = idx * 4;
        int b = (int)(f / 768000);
        int r2 = (int)(f % 768000);
        int t = r2 >> 9, e = r2 & 511;
        float4 vv = *reinterpret_cast<const float4*>(enc + f);
        ushort4 h4;
        h4.x = f2bf(vv.x); h4.y = f2bf(vv.y); h4.z = f2bf(vv.z); h4.w = f2bf(vv.w);
        size_t o = ((size_t)b * TP + t) * KAUG + e;
        *reinterpret_cast<ushort4*>(Ahi + o) = h4;
        if (((t & ~127) + 128) > xl[b]) {          // tile containing t runs 3-product
            ushort4 l4;
            l4.x = f2bf(vv.x - bf2f(h4.x));
            l4.y = f2bf(vv.y - bf2f(h4.y));
            l4.z = f2bf(vv.z - bf2f(h4.z));
            l4.w = f2bf(vv.w - bf2f(h4.w));
            *reinterpret_cast<ushort4*>(Alo + o) = l4;
        }
    }
}

// ---------- fused split-bf16 MFMA GEMM + (+dec_a, tanh, *v, reduce-A) -> energy ----------
// 3-product (hi*hi + hi*lo + lo*hi) only for tiles containing padded rows (t >= xlen),
// where the reference's *(-1024) mask amplifies energy error x1024 in the logits.
// Fully-valid tiles run plain hi*hi: logit error ~3e-3 -> aw relative error <1%.
__global__ __launch_bounds__(256) void k_gemm(
    const unsigned short* __restrict__ Ahi, const unsigned short* __restrict__ Alo,
    const unsigned short* __restrict__ Whi, const unsigned short* __restrict__ Wlo,
    const float* __restrict__ dec_a, const float* __restrict__ vvec,
    const int* __restrict__ xl, float* __restrict__ energy) {
    __shared__ unsigned short lsAhi[128 * 32], lsAlo[128 * 32];
    __shared__ unsigned short lsBhi[128 * 32], lsBlo[128 * 32];
    const int ntile = blockIdx.x, mtile = blockIdx.y, b = blockIdx.z;
    const int tid = threadIdx.x;
    const int lane = tid & 63, wave = tid >> 6;
    const int wm = wave >> 1, wn = wave & 1;
    const int m0 = mtile * 128, n0 = ntile * 128;
    const int xlen = xl[b];

    f32x4 acc[4][4];
#pragma unroll
    for (int i = 0; i < 4; i++)
#pragma unroll
        for (int j = 0; j < 4; j++) acc[i][j] = (f32x4){0.f, 0.f, 0.f, 0.f};

    const int row = tid >> 2;
    const int ko  = (tid & 3) * 8;
    const size_t abase = ((size_t)b * TP + m0 + row) * KAUG + ko;
    const size_t bbase = ((size_t)n0 + row) * KAUG + ko;
    const int l1 = row * 32 + ko;        // == tid*8 elements == tid*16 bytes (wave-uniform+lane*16)
    const int l2 = l1 + 64 * 32;
    const int ar = wm * 64, br = wn * 64;
    const int fo = (lane & 15) * 32 + (lane >> 4) * 8;

    if (m0 + 128 > xlen) {
        // ---- 3-product path (tile contains padded rows) ----
        for (int ks = 0; ks < 18; ++ks) {
            const int k0 = ks * 32;
            __syncthreads();
            glds16(Ahi + abase + k0,                     &lsAhi[l1]);
            glds16(Ahi + abase + k0 + (size_t)64 * KAUG, &lsAhi[l2]);
            glds16(Alo + abase + k0,                     &lsAlo[l1]);
            glds16(Alo + abase + k0 + (size_t)64 * KAUG, &lsAlo[l2]);
            glds16(Whi + bbase + k0,                     &lsBhi[l1]);
            glds16(Whi + bbase + k0 + (size_t)64 * KAUG, &lsBhi[l2]);
            glds16(Wlo + bbase + k0,                     &lsBlo[l1]);
            glds16(Wlo + bbase + k0 + (size_t)64 * KAUG, &lsBlo[l2]);
            asm volatile("s_waitcnt vmcnt(0)" ::: "memory");
            __syncthreads();

            bf16x8 ah[4], al[4], bh[4], bl[4];
#pragma unroll
            for (int i = 0; i < 4; i++) {
                ah[i] = *(const bf16x8*)&lsAhi[(ar + i * 16) * 32 + fo];
                al[i] = *(const bf16x8*)&lsAlo[(ar + i * 16) * 32 + fo];
                bh[i] = *(const bf16x8*)&lsBhi[(br + i * 16) * 32 + fo];
                bl[i] = *(const bf16x8*)&lsBlo[(br + i * 16) * 32 + fo];
            }
#pragma unroll
            for (int i = 0; i < 4; i++)
#pragma unroll
                for (int j = 0; j < 4; j++) {
                    acc[i][j] = __builtin_amdgcn_mfma_f32_16x16x32_bf16(ah[i], bh[j], acc[i][j], 0, 0, 0);
                    acc[i][j] = __builtin_amdgcn_mfma_f32_16x16x32_bf16(ah[i], bl[j], acc[i][j], 0, 0, 0);
                    acc[i][j] = __builtin_amdgcn_mfma_f32_16x16x32_bf16(al[i], bh[j], acc[i][j], 0, 0, 0);
                }
        }
    } else {
        // ---- 1-product path (fully valid tile): half the staging, 1/3 the MFMA ----
        for (int ks = 0; ks < 18; ++ks) {
            const int k0 = ks * 32;
            __syncthreads();
            glds16(Ahi + abase + k0,                     &lsAhi[l1]);
            glds16(Ahi + abase + k0 + (size_t)64 * KAUG, &lsAhi[l2]);
            glds16(Whi + bbase + k0,                     &lsBhi[l1]);
            glds16(Whi + bbase + k0 + (size_t)64 * KAUG, &lsBhi[l2]);
            asm volatile("s_waitcnt vmcnt(0)" ::: "memory");
            __syncthreads();

            bf16x8 ah[4], bh[4];
#pragma unroll
            for (int i = 0; i < 4; i++) {
                ah[i] = *(const bf16x8*)&lsAhi[(ar + i * 16) * 32 + fo];
                bh[i] = *(const bf16x8*)&lsBhi[(br + i * 16) * 32 + fo];
            }
#pragma unroll
            for (int i = 0; i < 4; i++)
#pragma unroll
                for (int j = 0; j < 4; j++)
                    acc[i][j] = __builtin_amdgcn_mfma_f32_16x16x32_bf16(ah[i], bh[j], acc[i][j], 0, 0, 0);
        }
    }

    // Epilogue: x = acc + dec_a[b][n]; energy += tanh(x)*v[n], reduced over head's A-dim
    const int h = ntile >> 2;            // 128-wide tile lies inside one head (512 cols)
    const int kg = lane >> 4;
    float dv[4], vv[4];
#pragma unroll
    for (int j = 0; j < 4; j++) {
        int ng = n0 + wn * 64 + j * 16 + (lane & 15);
        dv[j] = dec_a[(size_t)b * NN + ng];
        vv[j] = vvec[ng];
    }
#pragma unroll
    for (int i = 0; i < 4; i++) {
        float part[4] = {0.f, 0.f, 0.f, 0.f};
#pragma unroll
        for (int j = 0; j < 4; j++)
#pragma unroll
            for (int r = 0; r < 4; r++)
                part[r] += tanhf(acc[i][j][r] + dv[j]) * vv[j];
#pragma unroll
        for (int r = 0; r < 4; r++) {
            float s = part[r];
            s += __shfl_xor(s, 1, 64);
            s += __shfl_xor(s, 2, 64);
            s += __shfl_xor(s, 4, 64);
            s += __shfl_xor(s, 8, 64);
            if ((lane & 15) == 0) {
                int t = m0 + wm * 64 + i * 16 + kg * 4 + r;
                if (t < TT)
                    atomicAdd(&energy[((size_t)b * HH + h) * TP + t], s);
            }
        }
    }
}

// ---------- masked softmax over time (replicates energy * (+1 / -1024) mask) ----------
__global__ __launch_bounds__(512) void k_softmax(const float* __restrict__ energy,
                                                 const int* __restrict__ x_lens,
                                                 float* __restrict__ aw) {
    const int b = blockIdx.x >> 2, h = blockIdx.x & 3;
    const int tid = threadIdx.x;
    __shared__ float sE[TT];
    __shared__ float red[512];
    const int xlen = x_lens[b];
    float lmax = -3.4e38f;
    for (int t = tid; t < TT; t += 512) {
        float e = energy[((size_t)b * HH + h) * TP + t];
        float m = (t < xlen) ? e : e * -1024.0f;
        sE[t] = m;
        lmax = fmaxf(lmax, m);
    }
    red[tid] = lmax; __syncthreads();
    for (int s = 256; s > 0; s >>= 1) { if (tid < s) red[tid] = fmaxf(red[tid], red[tid + s]); __syncthreads(); }
    float mx = red[0]; __syncthreads();
    float lsum = 0.f;
    for (int t = tid; t < TT; t += 512) {
        float ex = expf(sE[t] - mx);
        sE[t] = ex; lsum += ex;
    }
    red[tid] = lsum; __syncthreads();
    for (int s = 256; s > 0; s >>= 1) { if (tid < s) red[tid] += red[tid + s]; __syncthreads(); }
    float sum = red[0];
    for (int t = tid; t < TT; t += 512)
        aw[((size_t)b * TT + t) * HH + h] = sE[t] / sum;
}

// ---------- ctx_h[b][h][e] = sum_t aw[b][t][h] * enc[b][t][e] ----------
__global__ __launch_bounds__(512) void k_ctx(const float* __restrict__ enc,
                                             const float* __restrict__ aw,
                                             float* __restrict__ ctx_h) {
    const int chunk = blockIdx.x, b = blockIdx.y;
    const int t0 = chunk * 128;
    const int nt = (TT - t0 < 128) ? (TT - t0) : 128;
    __shared__ float sA[128 * 4];
    const int tid = threadIdx.x;
    for (int i = tid; i < nt * 4; i += 512)
        sA[i] = aw[((size_t)b * TT + t0) * HH + i];
    __syncthreads();
    float a0 = 0.f, a1 = 0.f, a2 = 0.f, a3 = 0.f;
    const float* ep = enc + ((size_t)b * TT + t0) * EE + tid;
    for (int tt = 0; tt < nt; ++tt) {
        float ev = ep[(size_t)tt * EE];
        a0 += sA[tt * 4 + 0] * ev; a1 += sA[tt * 4 + 1] * ev;
        a2 += sA[tt * 4 + 2] * ev; a3 += sA[tt * 4 + 3] * ev;
    }
    atomicAdd(&ctx_h[((size_t)b * HH + 0) * EE + tid], a0);
    atomicAdd(&ctx_h[((size_t)b * HH + 1) * EE + tid], a1);
    atomicAdd(&ctx_h[((size_t)b * HH + 2) * EE + tid], a2);
    atomicAdd(&ctx_h[((size_t)b * HH + 3) * EE + tid], a3);
}

// ---------- ctx = ctx_h @ w_mha + b_mha ----------
__global__ void k_mha(const float* __restrict__ ctx_h, const float* __restrict__ w_mha,
                      const float* __restrict__ b_mha, float* __restrict__ out) {
    int idx = blockIdx.x * 256 + threadIdx.x;   // 16384
    int b = idx >> 9, eo = idx & 511;
    float acc = b_mha[eo];
    const float* c = ctx_h + (size_t)b * NN;
    for (int k = 0; k < NN; ++k) acc += c[k] * w_mha[(size_t)k * EE + eo];
    out[(size_t)b * EE + eo] = acc;
}

extern "C" void kernel_launch(void* const* d_in, const int* in_sizes, int n_in,
                              void* d_out, int out_size, void* d_ws, size_t ws_size,
                              hipStream_t stream) {
    (void)in_sizes; (void)n_in; (void)out_size;
    const float* enc    = (const float*)d_in[0];
    const int*   xlen   = (const int*)d_in[1];
    const float* dec    = (const float*)d_in[2];
    const float* aw_in  = (const float*)d_in[3];
    const float* w_enc  = (const float*)d_in[4];
    const float* b_enc  = (const float*)d_in[5];
    const float* w_dec  = (const float*)d_in[6];
    const float* w_conv = (const float*)d_in[7];
    const float* convk  = (const float*)d_in[8];
    const float* v      = (const float*)d_in[9];
    const float* w_mha  = (const float*)d_in[10];
    const float* b_mha  = (const float*)d_in[11];
    float* out = (float*)d_out;

    // ws layout (needs ~119.3 MB)
    char* ws = (char*)d_ws;
    unsigned short* Whi = (unsigned short*)ws;                          // 2,359,296 B
    unsigned short* Wlo = Whi + (size_t)NN * KAUG;                      // 2,359,296 B
    unsigned short* Ahi = (unsigned short*)(ws + 4718592);              // 56,623,104 B
    unsigned short* Alo = Ahi + (size_t)BB * TP * KAUG;                 // 56,623,104 B
    float* dec_a  = (float*)(ws + 117964800);                           //   262,144 B
    float* energy = (float*)(ws + 118226944);                           //   786,432 B
    float* ctx_h  = (float*)(ws + 119013376);                           //   262,144 B
    (void)ws_size;

    hipMemsetAsync(energy, 0, 786432 + 262144, stream);  // energy + ctx_h (contiguous)

    k_prep<<<dim3(PREP_TOTAL), 256, 0, stream>>>(enc, xlen, dec, aw_in, w_enc, b_enc,
                                                 w_dec, w_conv, convk,
                                                 Whi, Wlo, Ahi, Alo, dec_a);
    k_gemm<<<dim3(16, 12, BB), 256, 0, stream>>>(Ahi, Alo, Whi, Wlo, dec_a, v, xlen, energy);
    k_softmax<<<dim3(BB * HH), 512, 0, stream>>>(energy, xlen, out + 16384);
    k_ctx <<<dim3(12, BB), 512, 0, stream>>>(enc, out + 16384, ctx_h);
    k_mha <<<dim3(64), 256, 0, stream>>>(ctx_h, w_mha, b_mha, out);
}

// Round 3
// 597.099 us; speedup vs baseline: 1.3173x; 1.1034x over previous
//
#include <hip/hip_runtime.h>
#include <hip/hip_bf16.h>

// Problem constants
#define BB 32
#define TT 1500
#define TP 1536      // T padded to 12*128 for GEMM tiles
#define EE 512
#define HH 4
#define AA 512
#define NN 2048      // H*A
#define CC 10
#define KCONV 201
#define KAUG 576     // 512 enc + 40 conv + 24 zero pad (18 k-steps of 32)

typedef __attribute__((ext_vector_type(8))) __bf16 bf16x8;
typedef __attribute__((ext_vector_type(4))) float f32x4;

// ---------- helpers ----------
__device__ __forceinline__ unsigned short f2bf(float x) {
    unsigned int u = __float_as_uint(x);
    u = (u + 0x7fffu + ((u >> 16) & 1u)) >> 16;   // RNE, inputs always finite
    return (unsigned short)u;
}
__device__ __forceinline__ float bf2f(unsigned short u) {
    return __uint_as_float(((unsigned int)u) << 16);
}
__device__ __forceinline__ void glds16(const void* g, void* l) {
    __builtin_amdgcn_global_load_lds(
        (const __attribute__((address_space(1))) unsigned int*)g,
        (__attribute__((address_space(3))) unsigned int*)l, 16, 0, 0);
}
// tanh(x) = 1 - 2/(e^{2x}+1); v_exp_f32+v_rcp_f32, ~5 VALU insts.
// Saturates correctly: 2x large -> e=inf -> rcp=0 -> 1; 2x very negative -> e=0 -> -1.
// abs error ~1e-6 (<< the 4e-5 budget set by the x(-1024) logit amplification).
__device__ __forceinline__ float tanh_fast(float x) {
    float e = __expf(x * 2.0f);
    return fmaf(-2.0f, __builtin_amdgcn_rcpf(e + 1.0f), 1.0f);
}

// Fused prep kernel: block-range dispatch of 5 independent phases.
//   [0,1024)           dec   dec_a[b][n]  (4-way K-split + LDS reduce)
//   [1024,8704)        conv  grouped conv -> A cols [512,552)
//   [8704,13312)       wt    W planes
//   [13312,20404)      pad   zero-fill A padding
//   [20404,44404)      enc   enc f32 -> A cols [0,512) (Alo gated on tile validity)
#define PREP_DEC0   0
#define PREP_CONV0  1024
#define PREP_WT0    8704
#define PREP_PAD0   13312
#define PREP_ENC0   20404
#define PREP_TOTAL  44404

__global__ __launch_bounds__(256) void k_prep(
    const float* __restrict__ enc, const int* __restrict__ xl,
    const float* __restrict__ dec_out, const float* __restrict__ aw_step,
    const float* __restrict__ w_enc, const float* __restrict__ b_enc,
    const float* __restrict__ w_dec, const float* __restrict__ w_conv,
    const float* __restrict__ conv_k,
    unsigned short* __restrict__ Whi, unsigned short* __restrict__ Wlo,
    unsigned short* __restrict__ Ahi, unsigned short* __restrict__ Alo,
    float* __restrict__ dec_a) {
    __shared__ float sbuf[456 + KCONV];
    const int bid = blockIdx.x;
    const int tid = threadIdx.x;

    if (bid < PREP_CONV0) {
        // ---- dec: dec_a[b][n] = b_enc[n] + sum_d dec[b][d]*w_dec[h][d][a] ----
        // 1024 blocks: b = bid>>5, 64 outputs each; 4-way split over d.
        const int b  = bid >> 5;
        const int n0 = (bid & 31) * 64;
        const int n  = n0 + (tid & 63);
        const int dg = tid >> 6;                   // 0..3, 128 d each
        const int h  = n >> 9, a = n & 511;
        const float* dp = dec_out + (size_t)b * 512 + dg * 128;
        const float* wp = w_dec + ((size_t)h * 512 + dg * 128) * 512 + a;
        float acc = 0.f;
#pragma unroll 8
        for (int d = 0; d < 128; ++d) acc += dp[d] * wp[(size_t)d * 512];
        sbuf[tid] = acc;
        __syncthreads();
        if (tid < 64) {
            float tot = sbuf[tid] + sbuf[tid + 64] + sbuf[tid + 128] + sbuf[tid + 192];
            dec_a[(size_t)b * NN + n0 + tid] = b_enc[n0 + tid] + tot;
        }
    } else if (bid < PREP_WT0) {
        // ---- conv: grouped 1D conv over aw_step -> A cols [512,552) ----
        int r = bid - PREP_CONV0;                  // 7680 = 6*40*32
        const int tch = r % 6;
        const int hc  = (r / 6) % 40;
        const int b   = r / 240;
        const int h   = hc / 10;
        const int t0  = tch * 256;
        float* sAw = sbuf;
        float* sK  = sbuf + 456;
        for (int i = tid; i < 456; i += 256) {
            int ts = t0 - 100 + i;
            sAw[i] = (ts >= 0 && ts < TT) ? aw_step[((size_t)b * TT + ts) * HH + h] : 0.f;
        }
        if (tid < KCONV) sK[tid] = conv_k[(size_t)hc * KCONV + tid];
        __syncthreads();
        int t = t0 + tid;
        if (t < TT) {
            float acc = 0.f;
            for (int k = 0; k < KCONV; ++k) acc += sAw[tid + k] * sK[k];
            size_t o = ((size_t)b * TP + t) * KAUG + 512 + hc;
            unsigned short hi = f2bf(acc);
            Ahi[o] = hi; Alo[o] = f2bf(acc - bf2f(hi));
        }
    } else if (bid < PREP_PAD0) {
        // ---- wt: W planes [N=2048][KAUG], hi/lo ----
        int idx = (bid - PREP_WT0) * 256 + tid;    // 1,179,648
        int n = idx / KAUG, k = idx % KAUG;
        int h = n >> 9, a = n & 511;
        float val = 0.f;
        if (k < 512) {
            val = w_enc[((size_t)h * 512 + k) * 512 + a];
        } else if (k < 552) {
            int j = k - 512; int h2 = j / 10, c = j % 10;
            if (h2 == h) val = w_conv[((size_t)h * 10 + c) * 512 + a];
        }
        unsigned short hi = f2bf(val);
        Whi[idx] = hi;
        Wlo[idx] = f2bf(val - bf2f(hi));
    } else if (bid < PREP_ENC0) {
        // ---- pad: zero rows >=1500 (all cols) + cols [552,576) (rows <1500) ----
        int idx = (bid - PREP_PAD0) * 256 + tid;
        const int tot1 = BB * 36 * KAUG;           // 663552
        const int tot2 = BB * TT * 24;             // 1152000
        size_t o;
        if (idx < tot1) {
            int b = idx / (36 * KAUG); int r2 = idx % (36 * KAUG);
            int t = 1500 + r2 / KAUG;  int k = r2 % KAUG;
            o = ((size_t)b * TP + t) * KAUG + k;
        } else if (idx < tot1 + tot2) {
            int j = idx - tot1;
            int b = j / (TT * 24); int r2 = j % (TT * 24);
            int t = r2 / 24;       int k = 552 + r2 % 24;
            o = ((size_t)b * TP + t) * KAUG + k;
        } else return;
        Ahi[o] = 0; Alo[o] = 0;
    } else {
        // ---- enc: f32 -> A planes cols [0,512); Alo only for 3-product tiles ----
        long idx = (long)(bid - PREP_ENC0) * 256 + tid;   // 6,144,000 float4s
        if (idx >= 6144000L) return;
        long f = idx * 4;
        int b = (int)(f / 768000);
        int r2 = (int)(f % 768000);
        int t = r2 >> 9, e = r2 & 511;
        float4 vv = *reinterpret_cast<const float4*>(enc + f);
        ushort4 h4;
        h4.x = f2bf(vv.x); h4.y = f2bf(vv.y); h4.z = f2bf(vv.z); h4.w = f2bf(vv.w);
        size_t o = ((size_t)b * TP + t) * KAUG + e;
        *reinterpret_cast<ushort4*>(Ahi + o) = h4;
        if (((t & ~127) + 128) > xl[b]) {          // tile containing t runs 3-product
            ushort4 l4;
            l4.x = f2bf(vv.x - bf2f(h4.x));
            l4.y = f2bf(vv.y - bf2f(h4.y));
            l4.z = f2bf(vv.z - bf2f(h4.z));
            l4.w = f2bf(vv.w - bf2f(h4.w));
            *reinterpret_cast<ushort4*>(Alo + o) = l4;
        }
    }
}

// ---------- fused split-bf16 MFMA GEMM + (+dec_a, tanh, *v, reduce-A) -> energy ----------
// 3-product (hi*hi + hi*lo + lo*hi) only for tiles containing padded rows (t >= xlen),
// where the reference's *(-1024) mask amplifies energy error x1024 in the logits.
// Fully-valid tiles run plain hi*hi: logit error ~3e-3 -> aw relative error <1%.
__global__ __launch_bounds__(256) void k_gemm(
    const unsigned short* __restrict__ Ahi, const unsigned short* __restrict__ Alo,
    const unsigned short* __restrict__ Whi, const unsigned short* __restrict__ Wlo,
    const float* __restrict__ dec_a, const float* __restrict__ vvec,
    const int* __restrict__ xl, float* __restrict__ energy) {
    __shared__ unsigned short lsAhi[128 * 32], lsAlo[128 * 32];
    __shared__ unsigned short lsBhi[128 * 32], lsBlo[128 * 32];
    const int ntile = blockIdx.x, mtile = blockIdx.y, b = blockIdx.z;
    const int tid = threadIdx.x;
    const int lane = tid & 63, wave = tid >> 6;
    const int wm = wave >> 1, wn = wave & 1;
    const int m0 = mtile * 128, n0 = ntile * 128;
    const int xlen = xl[b];

    f32x4 acc[4][4];
#pragma unroll
    for (int i = 0; i < 4; i++)
#pragma unroll
        for (int j = 0; j < 4; j++) acc[i][j] = (f32x4){0.f, 0.f, 0.f, 0.f};

    const int row = tid >> 2;
    const int ko  = (tid & 3) * 8;
    const size_t abase = ((size_t)b * TP + m0 + row) * KAUG + ko;
    const size_t bbase = ((size_t)n0 + row) * KAUG + ko;
    const int l1 = row * 32 + ko;        // == tid*8 elements == tid*16 bytes (wave-uniform+lane*16)
    const int l2 = l1 + 64 * 32;
    const int ar = wm * 64, br = wn * 64;
    const int fo = (lane & 15) * 32 + (lane >> 4) * 8;

    if (m0 + 128 > xlen) {
        // ---- 3-product path (tile contains padded rows) ----
        for (int ks = 0; ks < 18; ++ks) {
            const int k0 = ks * 32;
            __syncthreads();
            glds16(Ahi + abase + k0,                     &lsAhi[l1]);
            glds16(Ahi + abase + k0 + (size_t)64 * KAUG, &lsAhi[l2]);
            glds16(Alo + abase + k0,                     &lsAlo[l1]);
            glds16(Alo + abase + k0 + (size_t)64 * KAUG, &lsAlo[l2]);
            glds16(Whi + bbase + k0,                     &lsBhi[l1]);
            glds16(Whi + bbase + k0 + (size_t)64 * KAUG, &lsBhi[l2]);
            glds16(Wlo + bbase + k0,                     &lsBlo[l1]);
            glds16(Wlo + bbase + k0 + (size_t)64 * KAUG, &lsBlo[l2]);
            asm volatile("s_waitcnt vmcnt(0)" ::: "memory");
            __syncthreads();

            bf16x8 ah[4], al[4], bh[4], bl[4];
#pragma unroll
            for (int i = 0; i < 4; i++) {
                ah[i] = *(const bf16x8*)&lsAhi[(ar + i * 16) * 32 + fo];
                al[i] = *(const bf16x8*)&lsAlo[(ar + i * 16) * 32 + fo];
                bh[i] = *(const bf16x8*)&lsBhi[(br + i * 16) * 32 + fo];
                bl[i] = *(const bf16x8*)&lsBlo[(br + i * 16) * 32 + fo];
            }
#pragma unroll
            for (int i = 0; i < 4; i++)
#pragma unroll
                for (int j = 0; j < 4; j++) {
                    acc[i][j] = __builtin_amdgcn_mfma_f32_16x16x32_bf16(ah[i], bh[j], acc[i][j], 0, 0, 0);
                    acc[i][j] = __builtin_amdgcn_mfma_f32_16x16x32_bf16(ah[i], bl[j], acc[i][j], 0, 0, 0);
                    acc[i][j] = __builtin_amdgcn_mfma_f32_16x16x32_bf16(al[i], bh[j], acc[i][j], 0, 0, 0);
                }
        }
    } else {
        // ---- 1-product path (fully valid tile): half the staging, 1/3 the MFMA ----
        for (int ks = 0; ks < 18; ++ks) {
            const int k0 = ks * 32;
            __syncthreads();
            glds16(Ahi + abase + k0,                     &lsAhi[l1]);
            glds16(Ahi + abase + k0 + (size_t)64 * KAUG, &lsAhi[l2]);
            glds16(Whi + bbase + k0,                     &lsBhi[l1]);
            glds16(Whi + bbase + k0 + (size_t)64 * KAUG, &lsBhi[l2]);
            asm volatile("s_waitcnt vmcnt(0)" ::: "memory");
            __syncthreads();

            bf16x8 ah[4], bh[4];
#pragma unroll
            for (int i = 0; i < 4; i++) {
                ah[i] = *(const bf16x8*)&lsAhi[(ar + i * 16) * 32 + fo];
                bh[i] = *(const bf16x8*)&lsBhi[(br + i * 16) * 32 + fo];
            }
#pragma unroll
            for (int i = 0; i < 4; i++)
#pragma unroll
                for (int j = 0; j < 4; j++)
                    acc[i][j] = __builtin_amdgcn_mfma_f32_16x16x32_bf16(ah[i], bh[j], acc[i][j], 0, 0, 0);
        }
    }

    // Epilogue: x = acc + dec_a[b][n]; energy += tanh(x)*v[n], reduced over head's A-dim
    const int h = ntile >> 2;            // 128-wide tile lies inside one head (512 cols)
    const int kg = lane >> 4;
    float dv[4], vv[4];
#pragma unroll
    for (int j = 0; j < 4; j++) {
        int ng = n0 + wn * 64 + j * 16 + (lane & 15);
        dv[j] = dec_a[(size_t)b * NN + ng];
        vv[j] = vvec[ng];
    }
#pragma unroll
    for (int i = 0; i < 4; i++) {
        float part[4] = {0.f, 0.f, 0.f, 0.f};
#pragma unroll
        for (int j = 0; j < 4; j++)
#pragma unroll
            for (int r = 0; r < 4; r++)
                part[r] += tanh_fast(acc[i][j][r] + dv[j]) * vv[j];
#pragma unroll
        for (int r = 0; r < 4; r++) {
            float s = part[r];
            s += __shfl_xor(s, 1, 64);
            s += __shfl_xor(s, 2, 64);
            s += __shfl_xor(s, 4, 64);
            s += __shfl_xor(s, 8, 64);
            if ((lane & 15) == 0) {
                int t = m0 + wm * 64 + i * 16 + kg * 4 + r;
                if (t < TT)
                    atomicAdd(&energy[((size_t)b * HH + h) * TP + t], s);
            }
        }
    }
}

// ---------- masked softmax over time (replicates energy * (+1 / -1024) mask) ----------
__global__ __launch_bounds__(512) void k_softmax(const float* __restrict__ energy,
                                                 const int* __restrict__ x_lens,
                                                 float* __restrict__ aw) {
    const int b = blockIdx.x >> 2, h = blockIdx.x & 3;
    const int tid = threadIdx.x;
    __shared__ float sE[TT];
    __shared__ float red[512];
    const int xlen = x_lens[b];
    float lmax = -3.4e38f;
    for (int t = tid; t < TT; t += 512) {
        float e = energy[((size_t)b * HH + h) * TP + t];
        float m = (t < xlen) ? e : e * -1024.0f;
        sE[t] = m;
        lmax = fmaxf(lmax, m);
    }
    red[tid] = lmax; __syncthreads();
    for (int s = 256; s > 0; s >>= 1) { if (tid < s) red[tid] = fmaxf(red[tid], red[tid + s]); __syncthreads(); }
    float mx = red[0]; __syncthreads();
    float lsum = 0.f;
    for (int t = tid; t < TT; t += 512) {
        float ex = expf(sE[t] - mx);
        sE[t] = ex; lsum += ex;
    }
    red[tid] = lsum; __syncthreads();
    for (int s = 256; s > 0; s >>= 1) { if (tid < s) red[tid] += red[tid + s]; __syncthreads(); }
    float sum = red[0];
    for (int t = tid; t < TT; t += 512)
        aw[((size_t)b * TT + t) * HH + h] = sE[t] / sum;
}

// ---------- ctx_h[b][h][e] = sum_t aw[b][t][h] * enc[b][t][e] ----------
__global__ __launch_bounds__(512) void k_ctx(const float* __restrict__ enc,
                                             const float* __restrict__ aw,
                                             float* __restrict__ ctx_h) {
    const int chunk = blockIdx.x, b = blockIdx.y;
    const int t0 = chunk * 128;
    const int nt = (TT - t0 < 128) ? (TT - t0) : 128;
    __shared__ float sA[128 * 4];
    const int tid = threadIdx.x;
    for (int i = tid; i < nt * 4; i += 512)
        sA[i] = aw[((size_t)b * TT + t0) * HH + i];
    __syncthreads();
    float a0 = 0.f, a1 = 0.f, a2 = 0.f, a3 = 0.f;
    const float* ep = enc + ((size_t)b * TT + t0) * EE + tid;
    if (nt == 128) {
#pragma unroll 8
        for (int tt = 0; tt < 128; ++tt) {
            float ev = ep[(size_t)tt * EE];
            a0 += sA[tt * 4 + 0] * ev; a1 += sA[tt * 4 + 1] * ev;
            a2 += sA[tt * 4 + 2] * ev; a3 += sA[tt * 4 + 3] * ev;
        }
    } else {
        for (int tt = 0; tt < nt; ++tt) {
            float ev = ep[(size_t)tt * EE];
            a0 += sA[tt * 4 + 0] * ev; a1 += sA[tt * 4 + 1] * ev;
            a2 += sA[tt * 4 + 2] * ev; a3 += sA[tt * 4 + 3] * ev;
        }
    }
    atomicAdd(&ctx_h[((size_t)b * HH + 0) * EE + tid], a0);
    atomicAdd(&ctx_h[((size_t)b * HH + 1) * EE + tid], a1);
    atomicAdd(&ctx_h[((size_t)b * HH + 2) * EE + tid], a2);
    atomicAdd(&ctx_h[((size_t)b * HH + 3) * EE + tid], a3);
}

// ---------- ctx = ctx_h @ w_mha + b_mha ----------
// 128 blocks: b = bid>>2, 128 eo each; 2-way split over k + LDS reduce.
__global__ __launch_bounds__(256) void k_mha(const float* __restrict__ ctx_h,
                                             const float* __restrict__ w_mha,
                                             const float* __restrict__ b_mha,
                                             float* __restrict__ out) {
    __shared__ float sred[256];
    const int tid = threadIdx.x;
    const int b  = blockIdx.x >> 2;
    const int eo = ((blockIdx.x & 3) << 7) + (tid & 127);
    const int kg = tid >> 7;                   // 0..1, 1024 k each
    const float* c = ctx_h + (size_t)b * NN + kg * 1024;
    const float* w = w_mha + ((size_t)kg * 1024) * EE + eo;
    float acc = 0.f;
#pragma unroll 8
    for (int k = 0; k < 1024; ++k) acc += c[k] * w[(size_t)k * EE];
    sred[tid] = acc;
    __syncthreads();
    if (tid < 128)
        out[(size_t)b * EE + eo] = b_mha[eo] + sred[tid] + sred[tid + 128];
}

extern "C" void kernel_launch(void* const* d_in, const int* in_sizes, int n_in,
                              void* d_out, int out_size, void* d_ws, size_t ws_size,
                              hipStream_t stream) {
    (void)in_sizes; (void)n_in; (void)out_size;
    const float* enc    = (const float*)d_in[0];
    const int*   xlen   = (const int*)d_in[1];
    const float* dec    = (const float*)d_in[2];
    const float* aw_in  = (const float*)d_in[3];
    const float* w_enc  = (const float*)d_in[4];
    const float* b_enc  = (const float*)d_in[5];
    const float* w_dec  = (const float*)d_in[6];
    const float* w_conv = (const float*)d_in[7];
    const float* convk  = (const float*)d_in[8];
    const float* v      = (const float*)d_in[9];
    const float* w_mha  = (const float*)d_in[10];
    const float* b_mha  = (const float*)d_in[11];
    float* out = (float*)d_out;

    // ws layout (needs ~119.3 MB)
    char* ws = (char*)d_ws;
    unsigned short* Whi = (unsigned short*)ws;                          // 2,359,296 B
    unsigned short* Wlo = Whi + (size_t)NN * KAUG;                      // 2,359,296 B
    unsigned short* Ahi = (unsigned short*)(ws + 4718592);              // 56,623,104 B
    unsigned short* Alo = Ahi + (size_t)BB * TP * KAUG;                 // 56,623,104 B
    float* dec_a  = (float*)(ws + 117964800);                           //   262,144 B
    float* energy = (float*)(ws + 118226944);                           //   786,432 B
    float* ctx_h  = (float*)(ws + 119013376);                           //   262,144 B
    (void)ws_size;

    hipMemsetAsync(energy, 0, 786432 + 262144, stream);  // energy + ctx_h (contiguous)

    k_prep<<<dim3(PREP_TOTAL), 256, 0, stream>>>(enc, xlen, dec, aw_in, w_enc, b_enc,
                                                 w_dec, w_conv, convk,
                                                 Whi, Wlo, Ahi, Alo, dec_a);
    k_gemm<<<dim3(16, 12, BB), 256, 0, stream>>>(Ahi, Alo, Whi, Wlo, dec_a, v, xlen, energy);
    k_softmax<<<dim3(BB * HH), 512, 0, stream>>>(energy, xlen, out + 16384);
    k_ctx <<<dim3(12, BB), 512, 0, stream>>>(enc, out + 16384, ctx_h);
    k_mha <<<dim3(128), 256, 0, stream>>>(ctx_h, w_mha, b_mha, out);
}